// Round 15
// baseline (165.976 us; speedup 1.0000x reference)
//
#include <hip/hip_runtime.h>

// ---------------- problem dims ----------------
constexpr int B = 128, Cin = 64, H = 56, W = 56;
constexpr int Cout = 128, Ho = 28, Wo = 28;
constexpr int HW = Ho * Wo;                    // 784
constexpr int NPIX = B * HW;                   // 100352 output pixels
constexpr int NOUT = NPIX * Cout;              // 12,845,056
constexpr int NBLK2 = NPIX / 256;              // 392 conv blocks (divisible by 8)
constexpr float EPS_ = 1e-5f;
constexpr float CNT_ = (float)NPIX;

// padded layouts
constexpr int HPX = 57, WPX = 57;              // x padded (hi edge only), NHWC C=64
constexpr int HP1 = 30, WP1 = 30;              // y1 padded (1 both sides), NHWC C=128

typedef __attribute__((ext_vector_type(8))) unsigned short u16x8;
typedef __attribute__((ext_vector_type(4))) unsigned short u16x4;
typedef __attribute__((ext_vector_type(8))) short bf16x8;
typedef __attribute__((ext_vector_type(4))) float f32x4;

__device__ inline float bf2f(unsigned short u) {
    union { unsigned int i; float f; } v; v.i = ((unsigned int)u) << 16; return v.f;
}
__device__ inline unsigned short f2bf(float f) {
    union { float f; unsigned int i; } v; v.f = f;
    return (unsigned short)((v.i + 0x7fffu + ((v.i >> 16) & 1u)) >> 16);
}

__device__ inline void gload16(const void* g, void* l) {
    __builtin_amdgcn_global_load_lds(
        (const __attribute__((address_space(1))) unsigned int*)g,
        (__attribute__((address_space(3))) unsigned int*)l, 16, 0, 0);
}

// ================= conv2: 8-wave 256Mx128N, single-barrier ring-3, static K-loop =================
__global__ __launch_bounds__(512) void k_conv2_mfma(
        const unsigned short* __restrict__ xin,   // y1p padded NHWC [n][30][30][128]
        const unsigned short* __restrict__ wt,    // [co][1152]
        unsigned short* __restrict__ yout,        // y2b NCHW bf16
        float* __restrict__ part) {
    constexpr int CIN = 128, WP = 30, KTOT = 1152, NSTEP = 36;
    __shared__ unsigned short Alds[3][256 * 32];  // 48 KB
    __shared__ unsigned short Blds[3][128 * 32];  // 24 KB
    __shared__ float lsum[8][64], lsq[8][64];     // 4 KB
    const int tid = threadIdx.x, w = tid >> 6, l = tid & 63;
    const int wr = w >> 1, wc = w & 1;
    const int bid = (blockIdx.x & 7) * (NBLK2 / 8) + (blockIdx.x >> 3);  // XCD-chunked
    const int p0 = bid * 256;
    const char* xb = (const char*)xin;
    const char* wb = (const char*)wt;

    const int sslot = ((l & 3) ^ ((l >> 3) & 3)) * 16;   // T2 pre-swizzled source slot
    const int rswz  = ((l >> 4) ^ ((l >> 1) & 3)) * 16;  // matching read-side slot

    int gA[2], lofsA[2];
    #pragma unroll
    for (int i = 0; i < 2; ++i) {
        int row = w * 32 + i * 16 + (l >> 2);
        int p = p0 + row;
        int n = p / HW, rr = p % HW;
        int oh = rr / Wo, ow = rr % Wo;
        gA[i] = (((n * HP1 + oh) * WP + ow) * CIN) * 2 + sslot;
        lofsA[i] = row * 64 + (l & 3) * 16;
    }
    const int rowb = w * 16 + (l >> 2);
    const int gB = rowb * KTOT * 2 + sslot;
    const int lofsB = rowb * 64 + (l & 3) * 16;

    f32x4 acc[4][4];
    #pragma unroll
    for (int m = 0; m < 4; ++m)
        #pragma unroll
        for (int n = 0; n < 4; ++n)
            acc[m][n] = (f32x4){0.f, 0.f, 0.f, 0.f};

    gload16(xb + gA[0],      (char*)Alds[0] + lofsA[0]);
    gload16(xb + gA[1],      (char*)Alds[0] + lofsA[1]);
    gload16(wb + gB,         (char*)Blds[0] + lofsB);
    gload16(xb + gA[0] + 64, (char*)Alds[1] + lofsA[0]);
    gload16(xb + gA[1] + 64, (char*)Alds[1] + lofsA[1]);
    gload16(wb + gB + 64,    (char*)Blds[1] + lofsB);

    for (int oi = 0; oi < 3; ++oi) {                     // kh = oi
        const int Abase = oi * WP * CIN * 2;
        #pragma unroll
        for (int u = 0; u < 12; ++u) {
            const int s = oi * 12 + u;
            const int cur = u % 3;
            if (s + 1 < NSTEP) asm volatile("s_waitcnt vmcnt(3)" ::: "memory");
            else               asm volatile("s_waitcnt vmcnt(0)" ::: "memory");
            __builtin_amdgcn_s_barrier();
            if (s + 2 < NSTEP) {
                const int u2 = u + 2;
                const int j2 = u2 >> 2;
                const int c2 = u2 & 3;
                const int koffA = Abase + (j2 == 3 ? WP * CIN * 2 : j2 * CIN * 2) + c2 * 64;
                const int koffB = (s + 2) * 64;
                const int buf = u2 % 3;
                gload16(xb + gA[0] + koffA, (char*)Alds[buf] + lofsA[0]);
                gload16(xb + gA[1] + koffA, (char*)Alds[buf] + lofsA[1]);
                gload16(wb + gB + koffB,    (char*)Blds[buf] + lofsB);
            }
            bf16x8 bf[4];
            #pragma unroll
            for (int n = 0; n < 4; ++n)
                bf[n] = *(const bf16x8*)((const char*)Blds[cur] + (wc * 64 + n * 16 + (l & 15)) * 64 + rswz);
            #pragma unroll
            for (int m = 0; m < 4; ++m) {
                bf16x8 af = *(const bf16x8*)((const char*)Alds[cur] + (wr * 64 + m * 16 + (l & 15)) * 64 + rswz);
                #pragma unroll
                for (int n = 0; n < 4; ++n)
                    acc[m][n] = __builtin_amdgcn_mfma_f32_16x16x32_bf16(af, bf[n], acc[m][n], 0, 0, 0);
            }
        }
    }

    #pragma unroll
    for (int m = 0; m < 4; ++m) {
        int pq = p0 + wr * 64 + m * 16 + (l >> 4) * 4;
        int n = pq / HW, rr = pq % HW;
        #pragma unroll
        for (int q = 0; q < 4; ++q) {
            int co = wc * 64 + q * 16 + (l & 15);
            u16x4 v;
            #pragma unroll
            for (int r = 0; r < 4; ++r) v[r] = f2bf(acc[m][q][r]);
            *(u16x4*)(yout + ((size_t)(n * Cout + co)) * HW + rr) = v;
        }
    }

    float ps[4], pq_[4];
    #pragma unroll
    for (int n = 0; n < 4; ++n) {
        float s_ = 0.f, q_ = 0.f;
        #pragma unroll
        for (int m = 0; m < 4; ++m)
            #pragma unroll
            for (int r = 0; r < 4; ++r) { float v = acc[m][n][r]; s_ += v; q_ += v * v; }
        s_ += __shfl_xor(s_, 16); q_ += __shfl_xor(q_, 16);
        s_ += __shfl_xor(s_, 32); q_ += __shfl_xor(q_, 32);
        ps[n] = s_; pq_[n] = q_;
    }
    __syncthreads();
    if (l < 16) {
        #pragma unroll
        for (int n = 0; n < 4; ++n) { lsum[w][n * 16 + l] = ps[n]; lsq[w][n * 16 + l] = pq_[n]; }
    }
    __syncthreads();
    if (tid < 128) {
        int c = tid, half = c >> 6, j = c & 63;
        float s_ = 0.f, q_ = 0.f;
        #pragma unroll
        for (int r = 0; r < 4; ++r) { s_ += lsum[r * 2 + half][j]; q_ += lsq[r * 2 + half][j]; }
        part[((size_t)bid * 128 + c) * 2]     = s_;
        part[((size_t)bid * 128 + c) * 2 + 1] = q_;
    }
}

// ================= conv1 + fused DW: 8-wave 256Mx128N single-barrier ring-3 =================
__global__ __launch_bounds__(512) void k_conv1_mfma(
        const unsigned short* __restrict__ xin,   // xb padded NHWC [n][57][57][64]
        const unsigned short* __restrict__ wt,    // wt1 [co][576]
        const unsigned short* __restrict__ wtd,   // [co][64]
        unsigned short* __restrict__ yout,        // y1p padded NHWC
        unsigned short* __restrict__ ydout,       // ydb NCHW bf16
        float* __restrict__ part, float* __restrict__ partd) {
    constexpr int CIN = 64, WP = 57, KTOT = 576, NSTEP = 18;
    __shared__ unsigned short Alds[3][256 * 32];  // 48 KB
    __shared__ unsigned short Blds[3][128 * 32];  // 24 KB
    __shared__ float lsum[8][64], lsq[8][64];     // 4 KB
    const int tid = threadIdx.x, w = tid >> 6, l = tid & 63;
    const int wr = w >> 1, wc = w & 1;
    const int bid = (blockIdx.x & 7) * (NBLK2 / 8) + (blockIdx.x >> 3);
    const int p0 = bid * 256;
    const char* xb = (const char*)xin;
    const char* wb = (const char*)wt;

    const int sslot = ((l & 3) ^ ((l >> 3) & 3)) * 16;
    const int rswz  = ((l >> 4) ^ ((l >> 1) & 3)) * 16;

    int gA[2], lofsA[2];
    #pragma unroll
    for (int i = 0; i < 2; ++i) {
        int row = w * 32 + i * 16 + (l >> 2);
        int p = p0 + row;
        int n = p / HW, rr = p % HW;
        int oh = rr / Wo, ow = rr % Wo;
        gA[i] = (((n * HPX + oh * 2) * WP + ow * 2) * CIN) * 2 + sslot;
        lofsA[i] = row * 64 + (l & 3) * 16;
    }
    const int rowb = w * 16 + (l >> 2);
    const int gB = rowb * KTOT * 2 + sslot;
    const int lofsB = rowb * 64 + (l & 3) * 16;

    // DW B-fragments direct from global (bf16 [co][64])
    bf16x8 bd[2][4];
    #pragma unroll
    for (int s = 0; s < 2; ++s)
        #pragma unroll
        for (int n = 0; n < 4; ++n) {
            int co = wc * 64 + n * 16 + (l & 15);
            bd[s][n] = *(const bf16x8*)(wtd + co * 64 + s * 32 + (l >> 4) * 8);
        }

    f32x4 acc[4][4], accd[4][4];
    #pragma unroll
    for (int m = 0; m < 4; ++m)
        #pragma unroll
        for (int n = 0; n < 4; ++n) {
            acc[m][n]  = (f32x4){0.f, 0.f, 0.f, 0.f};
            accd[m][n] = (f32x4){0.f, 0.f, 0.f, 0.f};
        }

    #pragma unroll
    for (int s = 0; s < 2; ++s) {       // prologue: steps 0,1 (tap(0,0), c0 = 0/32)
        gload16(xb + gA[0] + s * 64, (char*)Alds[s] + lofsA[0]);
        gload16(xb + gA[1] + s * 64, (char*)Alds[s] + lofsA[1]);
        gload16(wb + gB + s * 64,    (char*)Blds[s] + lofsB);
    }

    #pragma unroll
    for (int s = 0; s < NSTEP; ++s) {
        const int cur = s % 3;
        if (s + 1 < NSTEP) asm volatile("s_waitcnt vmcnt(3)" ::: "memory");
        else               asm volatile("s_waitcnt vmcnt(0)" ::: "memory");
        __builtin_amdgcn_s_barrier();
        if (s + 2 < NSTEP) {
            const int s2 = s + 2;
            const int seg = s2 >> 1, kh = seg / 3, kw = seg % 3;
            const int koffA = (kh * WP + kw) * CIN * 2 + (s2 & 1) * 64;
            const int koffB = s2 * 64;
            const int buf = s2 % 3;
            gload16(xb + gA[0] + koffA, (char*)Alds[buf] + lofsA[0]);
            gload16(xb + gA[1] + koffA, (char*)Alds[buf] + lofsA[1]);
            gload16(wb + gB + koffB,    (char*)Blds[buf] + lofsB);
        }
        bf16x8 bf[4];
        #pragma unroll
        for (int n = 0; n < 4; ++n)
            bf[n] = *(const bf16x8*)((const char*)Blds[cur] + (wc * 64 + n * 16 + (l & 15)) * 64 + rswz);
        #pragma unroll
        for (int m = 0; m < 4; ++m) {
            bf16x8 af = *(const bf16x8*)((const char*)Alds[cur] + (wr * 64 + m * 16 + (l & 15)) * 64 + rswz);
            #pragma unroll
            for (int n = 0; n < 4; ++n)
                acc[m][n] = __builtin_amdgcn_mfma_f32_16x16x32_bf16(af, bf[n], acc[m][n], 0, 0, 0);
            if (s < 2) {
                #pragma unroll
                for (int n = 0; n < 4; ++n)
                    accd[m][n] = __builtin_amdgcn_mfma_f32_16x16x32_bf16(af, bd[s][n], accd[m][n], 0, 0, 0);
            }
        }
    }

    // ---- conv1 store: padded NHWC interior (+1,+1) ----
    #pragma unroll
    for (int m = 0; m < 4; ++m) {
        #pragma unroll
        for (int r = 0; r < 4; ++r) {
            int p = p0 + wr * 64 + m * 16 + (l >> 4) * 4 + r;
            int n = p / HW, rr = p % HW;
            int oh = rr / Wo, ow = rr % Wo;
            unsigned short* dst = yout + ((size_t)((n * HP1 + oh + 1) * WP1 + ow + 1)) * 128
                                 + wc * 64 + (l & 15);
            #pragma unroll
            for (int q = 0; q < 4; ++q)
                dst[q * 16] = f2bf(acc[m][q][r]);
        }
    }
    // ---- DW store: NCHW bf16 ----
    #pragma unroll
    for (int m = 0; m < 4; ++m) {
        int pq = p0 + wr * 64 + m * 16 + (l >> 4) * 4;
        int n = pq / HW, rr = pq % HW;
        #pragma unroll
        for (int q = 0; q < 4; ++q) {
            int co = wc * 64 + q * 16 + (l & 15);
            u16x4 v;
            #pragma unroll
            for (int r = 0; r < 4; ++r) v[r] = f2bf(accd[m][q][r]);
            *(u16x4*)(ydout + ((size_t)(n * Cout + co)) * HW + rr) = v;
        }
    }

    // ---- fused BN partials for both outputs ----
    #pragma unroll
    for (int pass = 0; pass < 2; ++pass) {
        f32x4 (&a)[4][4] = pass ? accd : acc;
        float* pt = pass ? partd : part;
        float ps[4], pq_[4];
        #pragma unroll
        for (int n = 0; n < 4; ++n) {
            float s_ = 0.f, q_ = 0.f;
            #pragma unroll
            for (int m = 0; m < 4; ++m)
                #pragma unroll
                for (int r = 0; r < 4; ++r) { float v = a[m][n][r]; s_ += v; q_ += v * v; }
            s_ += __shfl_xor(s_, 16); q_ += __shfl_xor(q_, 16);
            s_ += __shfl_xor(s_, 32); q_ += __shfl_xor(q_, 32);
            ps[n] = s_; pq_[n] = q_;
        }
        __syncthreads();
        if (l < 16) {
            #pragma unroll
            for (int n = 0; n < 4; ++n) { lsum[w][n * 16 + l] = ps[n]; lsq[w][n * 16 + l] = pq_[n]; }
        }
        __syncthreads();
        if (tid < 128) {
            int c = tid, half = c >> 6, j = c & 63;
            float s_ = 0.f, q_ = 0.f;
            #pragma unroll
            for (int r = 0; r < 4; ++r) { s_ += lsum[r * 2 + half][j]; q_ += lsq[r * 2 + half][j]; }
            pt[((size_t)bid * 128 + c) * 2]     = s_;
            pt[((size_t)bid * 128 + c) * 2 + 1] = q_;
        }
    }
}

// ---------------- border zeroing ----------------
__global__ __launch_bounds__(256) void k_zerob(unsigned short* __restrict__ xb,
                                               unsigned short* __restrict__ y1p) {
    int idx = blockIdx.x * 256 + threadIdx.x;
    constexpr int NA = B * 113 * 8;
    const u16x8 z = (u16x8){0, 0, 0, 0, 0, 0, 0, 0};
    if (idx < NA) {
        int cg = idx & 7; int t = idx >> 3;
        int bp = t % 113, n = t / 113;
        int ih = bp < 57 ? 56 : bp - 57;
        int iw = bp < 57 ? bp : 56;
        *(u16x8*)(xb + ((size_t)((n * HPX + ih) * WPX + iw)) * Cin + cg * 8) = z;
    } else {
        idx -= NA;
        if (idx >= B * 116 * 16) return;
        int cg = idx & 15; int t = idx >> 4;
        int bp = t % 116, n = t / 116;
        int oh, ow;
        if (bp < 30)      { oh = 0;           ow = bp; }
        else if (bp < 60) { oh = 29;          ow = bp - 30; }
        else if (bp < 88) { oh = bp - 60 + 1; ow = 0; }
        else              { oh = bp - 88 + 1; ow = 29; }
        *(u16x8*)(y1p + ((size_t)((n * HP1 + oh) * WP1 + ow)) * 128 + cg * 8) = z;
    }
}

// ---------------- layout prep: x NCHW f32 -> padded NHWC bf16, 2 rows/block ----------------
__global__ __launch_bounds__(512) void k_xprep(const float* __restrict__ x,
                                               unsigned short* __restrict__ xb) {
    __shared__ unsigned short lds[2][64 * 57];
    int n = blockIdx.x / (H / 2), ihp = blockIdx.x % (H / 2), ih0 = ihp * 2;
    const float* src = x + ((size_t)n * Cin * H + ih0) * W;
    for (int j = threadIdx.x; j < 2 * Cin * 14; j += 512) {
        int r = j / 896, rem = j % 896;
        int c = rem / 14, q = rem % 14;
        float4 v = *(const float4*)(src + ((size_t)c * H + r) * W + q * 4);
        unsigned short* d = &lds[r][c * 57 + q * 4];
        d[0] = f2bf(v.x); d[1] = f2bf(v.y); d[2] = f2bf(v.z); d[3] = f2bf(v.w);
    }
    __syncthreads();
    for (int k = threadIdx.x; k < 2 * W * 8; k += 512) {
        int r = k / 448, k2 = k % 448;
        int pix = k2 >> 3, cg = k2 & 7;
        u16x8 v;
        #pragma unroll
        for (int e = 0; e < 8; ++e) v[e] = lds[r][(cg * 8 + e) * 57 + pix];
        *(u16x8*)(xb + ((size_t)((n * HPX + ih0 + r) * WPX + pix)) * Cin + cg * 8) = v;
    }
}

__global__ void k_wprep_all(const float* __restrict__ w1, const float* __restrict__ w2,
                            const float* __restrict__ wd,
                            unsigned short* __restrict__ wt1, unsigned short* __restrict__ wt2,
                            unsigned short* __restrict__ wtd) {
    int idx = blockIdx.x * 256 + threadIdx.x;
    const float* w; unsigned short* wt; int cin, ntap;
    if (idx < 73728)            { w = w1; wt = wt1; cin = 64;  ntap = 9; }
    else if (idx < 73728 + 147456) { idx -= 73728; w = w2; wt = wt2; cin = 128; ntap = 9; }
    else if (idx < 73728 + 147456 + 8192) { idx -= 73728 + 147456; w = wd; wt = wtd; cin = 64; ntap = 1; }
    else return;
    int co = idx / (cin * ntap), r = idx % (cin * ntap);
    int ci = r / ntap, tap = r % ntap;
    wt[co * cin * ntap + tap * cin + ci] = f2bf(w[idx]);
}

// ---------------- BN finalize ----------------
__device__ inline void block_reduce2(float& s, float& s2) {
    #pragma unroll
    for (int off = 32; off > 0; off >>= 1) {
        s += __shfl_down(s, off);
        s2 += __shfl_down(s2, off);
    }
    __shared__ float ls[4], ls2[4];
    int wid = threadIdx.x >> 6, lane = threadIdx.x & 63;
    if (lane == 0) { ls[wid] = s; ls2[wid] = s2; }
    __syncthreads();
    if (threadIdx.x == 0) { s = ls[0] + ls[1] + ls[2] + ls[3]; s2 = ls2[0] + ls2[1] + ls2[2] + ls2[3]; }
}

__global__ __launch_bounds__(256) void k_finalize(
        const float* __restrict__ pA, const float* __restrict__ pB, int nA, int nB,
        const float* __restrict__ gA_, const float* __restrict__ bA_,
        const float* __restrict__ gB_, const float* __restrict__ bB_,
        float* __restrict__ scA, float* __restrict__ shA,
        float* __restrict__ scB, float* __restrict__ shB) {
    const bool second = blockIdx.x >= 128;
    const int c = blockIdx.x & 127;
    const float* part = second ? pB : pA;
    const int nblk = second ? nB : nA;
    const float* g = second ? gB_ : gA_;
    const float* b = second ? bB_ : bA_;
    float* scale = second ? scB : scA;
    float* shift = second ? shB : shA;
    float s = 0.f, q = 0.f;
    for (int k = threadIdx.x; k < nblk; k += 256) {
        s += part[((size_t)k * 128 + c) * 2];
        q += part[((size_t)k * 128 + c) * 2 + 1];
    }
    block_reduce2(s, q);
    if (threadIdx.x == 0) {
        float mean = s / CNT_;
        float var = q / CNT_ - mean * mean;
        float inv = rsqrtf(var + EPS_);
        scale[c] = g[c] * inv;
        shift[c] = b[c] - mean * g[c] * inv;
    }
}

// BN+ReLU in-place on y1p interior: 16 px/block, 8 ch-groups/thread
__global__ __launch_bounds__(256) void k_bnrelu(unsigned short* __restrict__ y,
        const float* __restrict__ sc, const float* __restrict__ sh) {
    int t = threadIdx.x, cg = t & 15, pl = t >> 4;
    int p = blockIdx.x * 16 + pl;
    int n = p / HW, rr = p % HW;
    int oh = rr / Wo, ow = rr % Wo;
    size_t a = ((size_t)((n * HP1 + oh + 1) * WP1 + ow + 1)) * 128 + cg * 8;
    u16x8 v = *(u16x8*)(y + a);
    u16x8 o;
    #pragma unroll
    for (int e = 0; e < 8; ++e) {
        float f = bf2f(v[e]) * sc[cg * 8 + e] + sh[cg * 8 + e];
        o[e] = f2bf(fmaxf(f, 0.f));
    }
    *(u16x8*)(y + a) = o;
}

// out = relu(bn2(y2) + bnd(yd)), bf16 NCHW -> f32 NCHW
__global__ __launch_bounds__(256) void k_final(
        const unsigned short* __restrict__ y2, const unsigned short* __restrict__ yd,
        const float* __restrict__ sc2, const float* __restrict__ sh2,
        const float* __restrict__ scd, const float* __restrict__ shd,
        float* __restrict__ out) {
    int idx = blockIdx.x * 256 + threadIdx.x;
    int plane = idx / (HW / 8);
    int c = plane & (Cout - 1);
    int i = idx % (HW / 8);
    size_t a = (size_t)plane * HW + i * 8;
    u16x8 v2 = *(const u16x8*)(y2 + a);
    u16x8 vd = *(const u16x8*)(yd + a);
    float s2c = sc2[c], h2c = sh2[c], sdc = scd[c], hdc = shd[c];
    float4 r0, r1;
    r0.x = fmaxf(bf2f(v2[0]) * s2c + h2c + bf2f(vd[0]) * sdc + hdc, 0.f);
    r0.y = fmaxf(bf2f(v2[1]) * s2c + h2c + bf2f(vd[1]) * sdc + hdc, 0.f);
    r0.z = fmaxf(bf2f(v2[2]) * s2c + h2c + bf2f(vd[2]) * sdc + hdc, 0.f);
    r0.w = fmaxf(bf2f(v2[3]) * s2c + h2c + bf2f(vd[3]) * sdc + hdc, 0.f);
    r1.x = fmaxf(bf2f(v2[4]) * s2c + h2c + bf2f(vd[4]) * sdc + hdc, 0.f);
    r1.y = fmaxf(bf2f(v2[5]) * s2c + h2c + bf2f(vd[5]) * sdc + hdc, 0.f);
    r1.z = fmaxf(bf2f(v2[6]) * s2c + h2c + bf2f(vd[6]) * sdc + hdc, 0.f);
    r1.w = fmaxf(bf2f(v2[7]) * s2c + h2c + bf2f(vd[7]) * sdc + hdc, 0.f);
    *(float4*)(out + a) = r0;
    *(float4*)(out + a + 4) = r1;
}

extern "C" void kernel_launch(void* const* d_in, const int* in_sizes, int n_in,
                              void* d_out, int out_size, void* d_ws, size_t ws_size,
                              hipStream_t stream) {
    const float* x  = (const float*)d_in[0];
    const float* w1 = (const float*)d_in[1];
    const float* g1 = (const float*)d_in[2];
    const float* b1 = (const float*)d_in[3];
    const float* w2 = (const float*)d_in[4];
    const float* g2 = (const float*)d_in[5];
    const float* b2 = (const float*)d_in[6];
    const float* wd = (const float*)d_in[7];
    const float* gd = (const float*)d_in[8];
    const float* bd = (const float*)d_in[9];
    float* out = (float*)d_out;

    char* ws = (char*)d_ws;
    auto alloc = [&](size_t bytes) { char* p = ws; ws += (bytes + 255) & ~(size_t)255; return p; };
    unsigned short* xb  = (unsigned short*)alloc((size_t)B * HPX * WPX * Cin * 2);
    unsigned short* y1p = (unsigned short*)alloc((size_t)B * HP1 * WP1 * Cout * 2);
    unsigned short* y2b = (unsigned short*)alloc((size_t)NOUT * 2);
    unsigned short* ydb = (unsigned short*)alloc((size_t)NOUT * 2);
    unsigned short* wt1 = (unsigned short*)alloc((size_t)Cout * 576 * 2);
    unsigned short* wt2 = (unsigned short*)alloc((size_t)Cout * 1152 * 2);
    unsigned short* wtd = (unsigned short*)alloc((size_t)Cout * 64 * 2);
    float* part1 = (float*)alloc((size_t)NBLK2 * 128 * 2 * 4);
    float* part2 = (float*)alloc((size_t)NBLK2 * 128 * 2 * 4);
    float* partd = (float*)alloc((size_t)NBLK2 * 128 * 2 * 4);
    float* sc1 = (float*)alloc(128 * 4); float* sh1 = (float*)alloc(128 * 4);
    float* sc2 = (float*)alloc(128 * 4); float* sh2 = (float*)alloc(128 * 4);
    float* scd = (float*)alloc(128 * 4); float* shd = (float*)alloc(128 * 4);

    k_zerob<<<(B * 113 * 8 + B * 116 * 16 + 255) / 256, 256, 0, stream>>>(xb, y1p);
    k_xprep<<<B * (H / 2), 512, 0, stream>>>(x, xb);
    k_wprep_all<<<(73728 + 147456 + 8192 + 255) / 256, 256, 0, stream>>>(w1, w2, wd, wt1, wt2, wtd);

    // conv1 (3x3 s2 -> padded NHWC) + fused 1x1-s2 downsample (-> NCHW), 8-wave
    k_conv1_mfma<<<NBLK2, 512, 0, stream>>>(xb, wt1, wtd, y1p, ydb, part1, partd);

    k_finalize<<<128, 256, 0, stream>>>(part1, part1, NBLK2, NBLK2,
                                        g1, b1, g1, b1, sc1, sh1, sc1, sh1);
    k_bnrelu<<<NPIX / 16, 256, 0, stream>>>(y1p, sc1, sh1);

    // conv2: 3x3 s1 -> NCHW bf16, 8-wave 256x128 single-barrier ring-3
    k_conv2_mfma<<<NBLK2, 512, 0, stream>>>(y1p, wt2, y2b, part2);

    k_finalize<<<256, 256, 0, stream>>>(part2, partd, NBLK2, NBLK2,
                                        g2, b2, gd, bd, sc2, sh2, scd, shd);

    k_final<<<NOUT / 8 / 256, 256, 0, stream>>>(y2b, ydb, sc2, sh2, scd, shd, out);
}

// Round 16
// 161.369 us; speedup vs baseline: 1.0286x; 1.0286x over previous
//
#include <hip/hip_runtime.h>

// ---------------- problem dims ----------------
constexpr int B = 128, Cin = 64, H = 56, W = 56;
constexpr int Cout = 128, Ho = 28, Wo = 28;
constexpr int HW = Ho * Wo;                    // 784
constexpr int NPIX = B * HW;                   // 100352 output pixels
constexpr int NOUT = NPIX * Cout;              // 12,845,056
constexpr int NBLK2 = NPIX / 256;              // 392 conv blocks (divisible by 8)
constexpr float EPS_ = 1e-5f;
constexpr float CNT_ = (float)NPIX;

// padded layouts
constexpr int HPX = 57, WPX = 57;              // x padded (hi edge only), NHWC C=64
constexpr int HP1 = 30, WP1 = 30;              // y1 padded (1 both sides), NHWC C=128

typedef __attribute__((ext_vector_type(8))) unsigned short u16x8;
typedef __attribute__((ext_vector_type(4))) unsigned short u16x4;
typedef __attribute__((ext_vector_type(8))) short bf16x8;
typedef __attribute__((ext_vector_type(4))) float f32x4;

__device__ inline float bf2f(unsigned short u) {
    union { unsigned int i; float f; } v; v.i = ((unsigned int)u) << 16; return v.f;
}
__device__ inline unsigned short f2bf(float f) {
    union { float f; unsigned int i; } v; v.f = f;
    return (unsigned short)((v.i + 0x7fffu + ((v.i >> 16) & 1u)) >> 16);
}

__device__ inline void gload16(const void* g, void* l) {
    __builtin_amdgcn_global_load_lds(
        (const __attribute__((address_space(1))) unsigned int*)g,
        (__attribute__((address_space(3))) unsigned int*)l, 16, 0, 0);
}

// ================= conv2: 8-wave 256Mx128N, single-barrier ring-3, static K-loop =================
__global__ __launch_bounds__(512) void k_conv2_mfma(
        const unsigned short* __restrict__ xin,   // y1p padded NHWC [n][30][30][128]
        const unsigned short* __restrict__ wt,    // [co][1152]
        unsigned short* __restrict__ yout,        // y2b NCHW bf16
        float* __restrict__ part) {
    constexpr int CIN = 128, WP = 30, KTOT = 1152, NSTEP = 36;
    __shared__ unsigned short Alds[3][256 * 32];  // 48 KB
    __shared__ unsigned short Blds[3][128 * 32];  // 24 KB
    __shared__ float lsum[8][64], lsq[8][64];     // 4 KB
    const int tid = threadIdx.x, w = tid >> 6, l = tid & 63;
    const int wr = w >> 1, wc = w & 1;
    const int bid = (blockIdx.x & 7) * (NBLK2 / 8) + (blockIdx.x >> 3);  // XCD-chunked
    const int p0 = bid * 256;
    const char* xb = (const char*)xin;
    const char* wb = (const char*)wt;

    const int sslot = ((l & 3) ^ ((l >> 3) & 3)) * 16;   // T2 pre-swizzled source slot
    const int rswz  = ((l >> 4) ^ ((l >> 1) & 3)) * 16;  // matching read-side slot

    int gA[2], lofsA[2];
    #pragma unroll
    for (int i = 0; i < 2; ++i) {
        int row = w * 32 + i * 16 + (l >> 2);
        int p = p0 + row;
        int n = p / HW, rr = p % HW;
        int oh = rr / Wo, ow = rr % Wo;
        gA[i] = (((n * HP1 + oh) * WP + ow) * CIN) * 2 + sslot;
        lofsA[i] = row * 64 + (l & 3) * 16;
    }
    const int rowb = w * 16 + (l >> 2);
    const int gB = rowb * KTOT * 2 + sslot;
    const int lofsB = rowb * 64 + (l & 3) * 16;

    f32x4 acc[4][4];
    #pragma unroll
    for (int m = 0; m < 4; ++m)
        #pragma unroll
        for (int n = 0; n < 4; ++n)
            acc[m][n] = (f32x4){0.f, 0.f, 0.f, 0.f};

    gload16(xb + gA[0],      (char*)Alds[0] + lofsA[0]);
    gload16(xb + gA[1],      (char*)Alds[0] + lofsA[1]);
    gload16(wb + gB,         (char*)Blds[0] + lofsB);
    gload16(xb + gA[0] + 64, (char*)Alds[1] + lofsA[0]);
    gload16(xb + gA[1] + 64, (char*)Alds[1] + lofsA[1]);
    gload16(wb + gB + 64,    (char*)Blds[1] + lofsB);

    for (int oi = 0; oi < 3; ++oi) {                     // kh = oi
        const int Abase = oi * WP * CIN * 2;
        #pragma unroll
        for (int u = 0; u < 12; ++u) {
            const int s = oi * 12 + u;
            const int cur = u % 3;
            if (s + 1 < NSTEP) asm volatile("s_waitcnt vmcnt(3)" ::: "memory");
            else               asm volatile("s_waitcnt vmcnt(0)" ::: "memory");
            __builtin_amdgcn_s_barrier();
            if (s + 2 < NSTEP) {
                const int u2 = u + 2;
                const int j2 = u2 >> 2;
                const int c2 = u2 & 3;
                const int koffA = Abase + (j2 == 3 ? WP * CIN * 2 : j2 * CIN * 2) + c2 * 64;
                const int koffB = (s + 2) * 64;
                const int buf = u2 % 3;
                gload16(xb + gA[0] + koffA, (char*)Alds[buf] + lofsA[0]);
                gload16(xb + gA[1] + koffA, (char*)Alds[buf] + lofsA[1]);
                gload16(wb + gB + koffB,    (char*)Blds[buf] + lofsB);
            }
            bf16x8 bf[4];
            #pragma unroll
            for (int n = 0; n < 4; ++n)
                bf[n] = *(const bf16x8*)((const char*)Blds[cur] + (wc * 64 + n * 16 + (l & 15)) * 64 + rswz);
            #pragma unroll
            for (int m = 0; m < 4; ++m) {
                bf16x8 af = *(const bf16x8*)((const char*)Alds[cur] + (wr * 64 + m * 16 + (l & 15)) * 64 + rswz);
                #pragma unroll
                for (int n = 0; n < 4; ++n)
                    acc[m][n] = __builtin_amdgcn_mfma_f32_16x16x32_bf16(af, bf[n], acc[m][n], 0, 0, 0);
            }
        }
    }

    #pragma unroll
    for (int m = 0; m < 4; ++m) {
        int pq = p0 + wr * 64 + m * 16 + (l >> 4) * 4;
        int n = pq / HW, rr = pq % HW;
        #pragma unroll
        for (int q = 0; q < 4; ++q) {
            int co = wc * 64 + q * 16 + (l & 15);
            u16x4 v;
            #pragma unroll
            for (int r = 0; r < 4; ++r) v[r] = f2bf(acc[m][q][r]);
            *(u16x4*)(yout + ((size_t)(n * Cout + co)) * HW + rr) = v;
        }
    }

    float ps[4], pq_[4];
    #pragma unroll
    for (int n = 0; n < 4; ++n) {
        float s_ = 0.f, q_ = 0.f;
        #pragma unroll
        for (int m = 0; m < 4; ++m)
            #pragma unroll
            for (int r = 0; r < 4; ++r) { float v = acc[m][n][r]; s_ += v; q_ += v * v; }
        s_ += __shfl_xor(s_, 16); q_ += __shfl_xor(q_, 16);
        s_ += __shfl_xor(s_, 32); q_ += __shfl_xor(q_, 32);
        ps[n] = s_; pq_[n] = q_;
    }
    __syncthreads();
    if (l < 16) {
        #pragma unroll
        for (int n = 0; n < 4; ++n) { lsum[w][n * 16 + l] = ps[n]; lsq[w][n * 16 + l] = pq_[n]; }
    }
    __syncthreads();
    if (tid < 128) {
        int c = tid, half = c >> 6, j = c & 63;
        float s_ = 0.f, q_ = 0.f;
        #pragma unroll
        for (int r = 0; r < 4; ++r) { s_ += lsum[r * 2 + half][j]; q_ += lsq[r * 2 + half][j]; }
        part[((size_t)bid * 128 + c) * 2]     = s_;
        part[((size_t)bid * 128 + c) * 2 + 1] = q_;
    }
}

// ================= conv1 + fused DW: 8-wave 256Mx128N single-barrier ring-3 =================
__global__ __launch_bounds__(512) void k_conv1_mfma(
        const unsigned short* __restrict__ xin,   // xb padded NHWC [n][57][57][64]
        const unsigned short* __restrict__ wt,    // wt1 [co][576]
        const unsigned short* __restrict__ wtd,   // [co][64]
        unsigned short* __restrict__ yout,        // y1p padded NHWC
        unsigned short* __restrict__ ydout,       // ydb NCHW bf16
        float* __restrict__ part, float* __restrict__ partd) {
    constexpr int CIN = 64, WP = 57, KTOT = 576, NSTEP = 18;
    __shared__ unsigned short Alds[3][256 * 32];  // 48 KB
    __shared__ unsigned short Blds[3][128 * 32];  // 24 KB
    __shared__ float lsum[8][64], lsq[8][64];     // 4 KB
    const int tid = threadIdx.x, w = tid >> 6, l = tid & 63;
    const int wr = w >> 1, wc = w & 1;
    const int bid = (blockIdx.x & 7) * (NBLK2 / 8) + (blockIdx.x >> 3);
    const int p0 = bid * 256;
    const char* xb = (const char*)xin;
    const char* wb = (const char*)wt;

    const int sslot = ((l & 3) ^ ((l >> 3) & 3)) * 16;
    const int rswz  = ((l >> 4) ^ ((l >> 1) & 3)) * 16;

    int gA[2], lofsA[2];
    #pragma unroll
    for (int i = 0; i < 2; ++i) {
        int row = w * 32 + i * 16 + (l >> 2);
        int p = p0 + row;
        int n = p / HW, rr = p % HW;
        int oh = rr / Wo, ow = rr % Wo;
        gA[i] = (((n * HPX + oh * 2) * WP + ow * 2) * CIN) * 2 + sslot;
        lofsA[i] = row * 64 + (l & 3) * 16;
    }
    const int rowb = w * 16 + (l >> 2);
    const int gB = rowb * KTOT * 2 + sslot;
    const int lofsB = rowb * 64 + (l & 3) * 16;

    // DW B-fragments direct from global (bf16 [co][64])
    bf16x8 bd[2][4];
    #pragma unroll
    for (int s = 0; s < 2; ++s)
        #pragma unroll
        for (int n = 0; n < 4; ++n) {
            int co = wc * 64 + n * 16 + (l & 15);
            bd[s][n] = *(const bf16x8*)(wtd + co * 64 + s * 32 + (l >> 4) * 8);
        }

    f32x4 acc[4][4], accd[4][4];
    #pragma unroll
    for (int m = 0; m < 4; ++m)
        #pragma unroll
        for (int n = 0; n < 4; ++n) {
            acc[m][n]  = (f32x4){0.f, 0.f, 0.f, 0.f};
            accd[m][n] = (f32x4){0.f, 0.f, 0.f, 0.f};
        }

    #pragma unroll
    for (int s = 0; s < 2; ++s) {       // prologue: steps 0,1 (tap(0,0), c0 = 0/32)
        gload16(xb + gA[0] + s * 64, (char*)Alds[s] + lofsA[0]);
        gload16(xb + gA[1] + s * 64, (char*)Alds[s] + lofsA[1]);
        gload16(wb + gB + s * 64,    (char*)Blds[s] + lofsB);
    }

    #pragma unroll
    for (int s = 0; s < NSTEP; ++s) {
        const int cur = s % 3;
        if (s + 1 < NSTEP) asm volatile("s_waitcnt vmcnt(3)" ::: "memory");
        else               asm volatile("s_waitcnt vmcnt(0)" ::: "memory");
        __builtin_amdgcn_s_barrier();
        if (s + 2 < NSTEP) {
            const int s2 = s + 2;
            const int seg = s2 >> 1, kh = seg / 3, kw = seg % 3;
            const int koffA = (kh * WP + kw) * CIN * 2 + (s2 & 1) * 64;
            const int koffB = s2 * 64;
            const int buf = s2 % 3;
            gload16(xb + gA[0] + koffA, (char*)Alds[buf] + lofsA[0]);
            gload16(xb + gA[1] + koffA, (char*)Alds[buf] + lofsA[1]);
            gload16(wb + gB + koffB,    (char*)Blds[buf] + lofsB);
        }
        bf16x8 bf[4];
        #pragma unroll
        for (int n = 0; n < 4; ++n)
            bf[n] = *(const bf16x8*)((const char*)Blds[cur] + (wc * 64 + n * 16 + (l & 15)) * 64 + rswz);
        #pragma unroll
        for (int m = 0; m < 4; ++m) {
            bf16x8 af = *(const bf16x8*)((const char*)Alds[cur] + (wr * 64 + m * 16 + (l & 15)) * 64 + rswz);
            #pragma unroll
            for (int n = 0; n < 4; ++n)
                acc[m][n] = __builtin_amdgcn_mfma_f32_16x16x32_bf16(af, bf[n], acc[m][n], 0, 0, 0);
            if (s < 2) {
                #pragma unroll
                for (int n = 0; n < 4; ++n)
                    accd[m][n] = __builtin_amdgcn_mfma_f32_16x16x32_bf16(af, bd[s][n], accd[m][n], 0, 0, 0);
            }
        }
    }

    // ---- conv1 store: padded NHWC interior (+1,+1) ----
    #pragma unroll
    for (int m = 0; m < 4; ++m) {
        #pragma unroll
        for (int r = 0; r < 4; ++r) {
            int p = p0 + wr * 64 + m * 16 + (l >> 4) * 4 + r;
            int n = p / HW, rr = p % HW;
            int oh = rr / Wo, ow = rr % Wo;
            unsigned short* dst = yout + ((size_t)((n * HP1 + oh + 1) * WP1 + ow + 1)) * 128
                                 + wc * 64 + (l & 15);
            #pragma unroll
            for (int q = 0; q < 4; ++q)
                dst[q * 16] = f2bf(acc[m][q][r]);
        }
    }
    // ---- DW store: NCHW bf16 ----
    #pragma unroll
    for (int m = 0; m < 4; ++m) {
        int pq = p0 + wr * 64 + m * 16 + (l >> 4) * 4;
        int n = pq / HW, rr = pq % HW;
        #pragma unroll
        for (int q = 0; q < 4; ++q) {
            int co = wc * 64 + q * 16 + (l & 15);
            u16x4 v;
            #pragma unroll
            for (int r = 0; r < 4; ++r) v[r] = f2bf(accd[m][q][r]);
            *(u16x4*)(ydout + ((size_t)(n * Cout + co)) * HW + rr) = v;
        }
    }

    // ---- fused BN partials for both outputs ----
    #pragma unroll
    for (int pass = 0; pass < 2; ++pass) {
        f32x4 (&a)[4][4] = pass ? accd : acc;
        float* pt = pass ? partd : part;
        float ps[4], pq_[4];
        #pragma unroll
        for (int n = 0; n < 4; ++n) {
            float s_ = 0.f, q_ = 0.f;
            #pragma unroll
            for (int m = 0; m < 4; ++m)
                #pragma unroll
                for (int r = 0; r < 4; ++r) { float v = a[m][n][r]; s_ += v; q_ += v * v; }
            s_ += __shfl_xor(s_, 16); q_ += __shfl_xor(q_, 16);
            s_ += __shfl_xor(s_, 32); q_ += __shfl_xor(q_, 32);
            ps[n] = s_; pq_[n] = q_;
        }
        __syncthreads();
        if (l < 16) {
            #pragma unroll
            for (int n = 0; n < 4; ++n) { lsum[w][n * 16 + l] = ps[n]; lsq[w][n * 16 + l] = pq_[n]; }
        }
        __syncthreads();
        if (tid < 128) {
            int c = tid, half = c >> 6, j = c & 63;
            float s_ = 0.f, q_ = 0.f;
            #pragma unroll
            for (int r = 0; r < 4; ++r) { s_ += lsum[r * 2 + half][j]; q_ += lsq[r * 2 + half][j]; }
            pt[((size_t)bid * 128 + c) * 2]     = s_;
            pt[((size_t)bid * 128 + c) * 2 + 1] = q_;
        }
    }
}

// ---------------- merged prep: borders zeroing + all weight repacks ----------------
constexpr int NZA = B * 113 * 8;            // xb border u16x8 stores
constexpr int NZB = B * 116 * 16;           // y1p border u16x8 stores
constexpr int NWP = 73728 + 147456 + 8192;  // weight elements
__global__ __launch_bounds__(256) void k_prep(
        unsigned short* __restrict__ xb, unsigned short* __restrict__ y1p,
        const float* __restrict__ w1, const float* __restrict__ w2,
        const float* __restrict__ wd,
        unsigned short* __restrict__ wt1, unsigned short* __restrict__ wt2,
        unsigned short* __restrict__ wtd) {
    int idx = blockIdx.x * 256 + threadIdx.x;
    const u16x8 z = (u16x8){0, 0, 0, 0, 0, 0, 0, 0};
    if (idx < NZA) {
        int cg = idx & 7; int t = idx >> 3;
        int bp = t % 113, n = t / 113;
        int ih = bp < 57 ? 56 : bp - 57;
        int iw = bp < 57 ? bp : 56;
        *(u16x8*)(xb + ((size_t)((n * HPX + ih) * WPX + iw)) * Cin + cg * 8) = z;
    } else if (idx < NZA + NZB) {
        idx -= NZA;
        int cg = idx & 15; int t = idx >> 4;
        int bp = t % 116, n = t / 116;
        int oh, ow;
        if (bp < 30)      { oh = 0;           ow = bp; }
        else if (bp < 60) { oh = 29;          ow = bp - 30; }
        else if (bp < 88) { oh = bp - 60 + 1; ow = 0; }
        else              { oh = bp - 88 + 1; ow = 29; }
        *(u16x8*)(y1p + ((size_t)((n * HP1 + oh) * WP1 + ow)) * 128 + cg * 8) = z;
    } else {
        idx -= NZA + NZB;
        if (idx >= NWP) return;
        const float* w; unsigned short* wt; int cin, ntap;
        if (idx < 73728)               { w = w1; wt = wt1; cin = 64;  ntap = 9; }
        else if (idx < 73728 + 147456) { idx -= 73728; w = w2; wt = wt2; cin = 128; ntap = 9; }
        else                           { idx -= 73728 + 147456; w = wd; wt = wtd; cin = 64; ntap = 1; }
        int co = idx / (cin * ntap), r = idx % (cin * ntap);
        int ci = r / ntap, tap = r % ntap;
        wt[co * cin * ntap + tap * cin + ci] = f2bf(w[idx]);
    }
}

// ---------------- layout prep: x NCHW f32 -> padded NHWC bf16, 2 rows/block ----------------
__global__ __launch_bounds__(512) void k_xprep(const float* __restrict__ x,
                                               unsigned short* __restrict__ xb) {
    __shared__ unsigned short lds[2][64 * 57];
    int n = blockIdx.x / (H / 2), ihp = blockIdx.x % (H / 2), ih0 = ihp * 2;
    const float* src = x + ((size_t)n * Cin * H + ih0) * W;
    for (int j = threadIdx.x; j < 2 * Cin * 14; j += 512) {
        int r = j / 896, rem = j % 896;
        int c = rem / 14, q = rem % 14;
        float4 v = *(const float4*)(src + ((size_t)c * H + r) * W + q * 4);
        unsigned short* d = &lds[r][c * 57 + q * 4];
        d[0] = f2bf(v.x); d[1] = f2bf(v.y); d[2] = f2bf(v.z); d[3] = f2bf(v.w);
    }
    __syncthreads();
    for (int k = threadIdx.x; k < 2 * W * 8; k += 512) {
        int r = k / 448, k2 = k % 448;
        int pix = k2 >> 3, cg = k2 & 7;
        u16x8 v;
        #pragma unroll
        for (int e = 0; e < 8; ++e) v[e] = lds[r][(cg * 8 + e) * 57 + pix];
        *(u16x8*)(xb + ((size_t)((n * HPX + ih0 + r) * WPX + pix)) * Cin + cg * 8) = v;
    }
}

// ---------------- BN finalize ----------------
__device__ inline void block_reduce2(float& s, float& s2) {
    #pragma unroll
    for (int off = 32; off > 0; off >>= 1) {
        s += __shfl_down(s, off);
        s2 += __shfl_down(s2, off);
    }
    __shared__ float ls[4], ls2[4];
    int wid = threadIdx.x >> 6, lane = threadIdx.x & 63;
    if (lane == 0) { ls[wid] = s; ls2[wid] = s2; }
    __syncthreads();
    if (threadIdx.x == 0) { s = ls[0] + ls[1] + ls[2] + ls[3]; s2 = ls2[0] + ls2[1] + ls2[2] + ls2[3]; }
}

__global__ __launch_bounds__(256) void k_finalize(
        const float* __restrict__ pA, const float* __restrict__ pB, int nA, int nB,
        const float* __restrict__ gA_, const float* __restrict__ bA_,
        const float* __restrict__ gB_, const float* __restrict__ bB_,
        float* __restrict__ scA, float* __restrict__ shA,
        float* __restrict__ scB, float* __restrict__ shB) {
    const bool second = blockIdx.x >= 128;
    const int c = blockIdx.x & 127;
    const float* part = second ? pB : pA;
    const int nblk = second ? nB : nA;
    const float* g = second ? gB_ : gA_;
    const float* b = second ? bB_ : bA_;
    float* scale = second ? scB : scA;
    float* shift = second ? shB : shA;
    float s = 0.f, q = 0.f;
    for (int k = threadIdx.x; k < nblk; k += 256) {
        s += part[((size_t)k * 128 + c) * 2];
        q += part[((size_t)k * 128 + c) * 2 + 1];
    }
    block_reduce2(s, q);
    if (threadIdx.x == 0) {
        float mean = s / CNT_;
        float var = q / CNT_ - mean * mean;
        float inv = rsqrtf(var + EPS_);
        scale[c] = g[c] * inv;
        shift[c] = b[c] - mean * g[c] * inv;
    }
}

// BN+ReLU in-place on y1p interior: 16 px/block, 8 ch-groups/thread
__global__ __launch_bounds__(256) void k_bnrelu(unsigned short* __restrict__ y,
        const float* __restrict__ sc, const float* __restrict__ sh) {
    int t = threadIdx.x, cg = t & 15, pl = t >> 4;
    int p = blockIdx.x * 16 + pl;
    int n = p / HW, rr = p % HW;
    int oh = rr / Wo, ow = rr % Wo;
    size_t a = ((size_t)((n * HP1 + oh + 1) * WP1 + ow + 1)) * 128 + cg * 8;
    u16x8 v = *(u16x8*)(y + a);
    u16x8 o;
    #pragma unroll
    for (int e = 0; e < 8; ++e) {
        float f = bf2f(v[e]) * sc[cg * 8 + e] + sh[cg * 8 + e];
        o[e] = f2bf(fmaxf(f, 0.f));
    }
    *(u16x8*)(y + a) = o;
}

// out = relu(bn2(y2) + bnd(yd)), bf16 NCHW -> f32 NCHW
__global__ __launch_bounds__(256) void k_final(
        const unsigned short* __restrict__ y2, const unsigned short* __restrict__ yd,
        const float* __restrict__ sc2, const float* __restrict__ sh2,
        const float* __restrict__ scd, const float* __restrict__ shd,
        float* __restrict__ out) {
    int idx = blockIdx.x * 256 + threadIdx.x;
    int plane = idx / (HW / 8);
    int c = plane & (Cout - 1);
    int i = idx % (HW / 8);
    size_t a = (size_t)plane * HW + i * 8;
    u16x8 v2 = *(const u16x8*)(y2 + a);
    u16x8 vd = *(const u16x8*)(yd + a);
    float s2c = sc2[c], h2c = sh2[c], sdc = scd[c], hdc = shd[c];
    float4 r0, r1;
    r0.x = fmaxf(bf2f(v2[0]) * s2c + h2c + bf2f(vd[0]) * sdc + hdc, 0.f);
    r0.y = fmaxf(bf2f(v2[1]) * s2c + h2c + bf2f(vd[1]) * sdc + hdc, 0.f);
    r0.z = fmaxf(bf2f(v2[2]) * s2c + h2c + bf2f(vd[2]) * sdc + hdc, 0.f);
    r0.w = fmaxf(bf2f(v2[3]) * s2c + h2c + bf2f(vd[3]) * sdc + hdc, 0.f);
    r1.x = fmaxf(bf2f(v2[4]) * s2c + h2c + bf2f(vd[4]) * sdc + hdc, 0.f);
    r1.y = fmaxf(bf2f(v2[5]) * s2c + h2c + bf2f(vd[5]) * sdc + hdc, 0.f);
    r1.z = fmaxf(bf2f(v2[6]) * s2c + h2c + bf2f(vd[6]) * sdc + hdc, 0.f);
    r1.w = fmaxf(bf2f(v2[7]) * s2c + h2c + bf2f(vd[7]) * sdc + hdc, 0.f);
    *(float4*)(out + a) = r0;
    *(float4*)(out + a + 4) = r1;
}

extern "C" void kernel_launch(void* const* d_in, const int* in_sizes, int n_in,
                              void* d_out, int out_size, void* d_ws, size_t ws_size,
                              hipStream_t stream) {
    const float* x  = (const float*)d_in[0];
    const float* w1 = (const float*)d_in[1];
    const float* g1 = (const float*)d_in[2];
    const float* b1 = (const float*)d_in[3];
    const float* w2 = (const float*)d_in[4];
    const float* g2 = (const float*)d_in[5];
    const float* b2 = (const float*)d_in[6];
    const float* wd = (const float*)d_in[7];
    const float* gd = (const float*)d_in[8];
    const float* bd = (const float*)d_in[9];
    float* out = (float*)d_out;

    char* ws = (char*)d_ws;
    auto alloc = [&](size_t bytes) { char* p = ws; ws += (bytes + 255) & ~(size_t)255; return p; };
    unsigned short* xb  = (unsigned short*)alloc((size_t)B * HPX * WPX * Cin * 2);
    unsigned short* y1p = (unsigned short*)alloc((size_t)B * HP1 * WP1 * Cout * 2);
    unsigned short* y2b = (unsigned short*)alloc((size_t)NOUT * 2);
    unsigned short* ydb = (unsigned short*)alloc((size_t)NOUT * 2);
    unsigned short* wt1 = (unsigned short*)alloc((size_t)Cout * 576 * 2);
    unsigned short* wt2 = (unsigned short*)alloc((size_t)Cout * 1152 * 2);
    unsigned short* wtd = (unsigned short*)alloc((size_t)Cout * 64 * 2);
    float* part1 = (float*)alloc((size_t)NBLK2 * 128 * 2 * 4);
    float* part2 = (float*)alloc((size_t)NBLK2 * 128 * 2 * 4);
    float* partd = (float*)alloc((size_t)NBLK2 * 128 * 2 * 4);
    float* sc1 = (float*)alloc(128 * 4); float* sh1 = (float*)alloc(128 * 4);
    float* sc2 = (float*)alloc(128 * 4); float* sh2 = (float*)alloc(128 * 4);
    float* scd = (float*)alloc(128 * 4); float* shd = (float*)alloc(128 * 4);

    k_prep<<<(NZA + NZB + NWP + 255) / 256, 256, 0, stream>>>(
        xb, y1p, w1, w2, wd, wt1, wt2, wtd);
    k_xprep<<<B * (H / 2), 512, 0, stream>>>(x, xb);

    // conv1 (3x3 s2 -> padded NHWC) + fused 1x1-s2 downsample (-> NCHW), 8-wave
    k_conv1_mfma<<<NBLK2, 512, 0, stream>>>(xb, wt1, wtd, y1p, ydb, part1, partd);

    k_finalize<<<128, 256, 0, stream>>>(part1, part1, NBLK2, NBLK2,
                                        g1, b1, g1, b1, sc1, sh1, sc1, sh1);
    k_bnrelu<<<NPIX / 16, 256, 0, stream>>>(y1p, sc1, sh1);

    // conv2: 3x3 s1 -> NCHW bf16, 8-wave 256x128 single-barrier ring-3
    k_conv2_mfma<<<NBLK2, 512, 0, stream>>>(y1p, wt2, y2b, part2);

    k_finalize<<<256, 256, 0, stream>>>(part2, partd, NBLK2, NBLK2,
                                        g2, b2, gd, bd, sc2, sh2, scd, shd);

    k_final<<<NOUT / 8 / 256, 256, 0, stream>>>(y2b, ydb, sc2, sh2, scd, shd, out);
}